// Round 1
// baseline (1331.891 us; speedup 1.0000x reference)
//
#include <hip/hip_runtime.h>

#define N_NODES 100000
#define N_EDGES 1600000
#define HIDDEN  128

// ---------------------------------------------------------------------------
// Kernel 1: per-node gate scalars. One 64-lane wave per node.
// lane l covers dims [2l, 2l+1]; shuffle-reduce the partial dots.
// ---------------------------------------------------------------------------
__global__ void fagcn_gates(const float* __restrict__ x,
                            const float* __restrict__ w1,
                            const float* __restrict__ w2,
                            float* __restrict__ g1,
                            float* __restrict__ g2) {
    const int wave = (int)((blockIdx.x * blockDim.x + threadIdx.x) >> 6);
    const int lane = (int)(threadIdx.x & 63);
    if (wave >= N_NODES) return;

    const float2 xv  = *reinterpret_cast<const float2*>(x  + (size_t)wave * HIDDEN + lane * 2);
    const float2 w1v = *reinterpret_cast<const float2*>(w1 + lane * 2);
    const float2 w2v = *reinterpret_cast<const float2*>(w2 + lane * 2);

    float s1 = xv.x * w1v.x + xv.y * w1v.y;
    float s2 = xv.x * w2v.x + xv.y * w2v.y;

    #pragma unroll
    for (int off = 32; off > 0; off >>= 1) {
        s1 += __shfl_down(s1, off, 64);
        s2 += __shfl_down(s2, off, 64);
    }
    if (lane == 0) {
        g1[wave] = s1;
        g2[wave] = s2;
    }
}

// ---------------------------------------------------------------------------
// Kernel 2: edge scatter. One 64-lane wave per edge (grid-strided).
// All lanes load the (wave-uniform) edge metadata -> broadcast loads.
// lane l gathers x[dst, 2l:2l+2] and atomically adds m*val into out[src].
// ---------------------------------------------------------------------------
__global__ void fagcn_edges(const float* __restrict__ x,
                            const float* __restrict__ adj,
                            const int*   __restrict__ in_idx,
                            const int*   __restrict__ out_idx,
                            const float* __restrict__ g1,
                            const float* __restrict__ g2,
                            float* __restrict__ out) {
    const int lane   = (int)(threadIdx.x & 63);
    const int gwave  = (int)((blockIdx.x * blockDim.x + threadIdx.x) >> 6);
    const int nwaves = (int)((gridDim.x * blockDim.x) >> 6);

    for (int e = gwave; e < N_EDGES; e += nwaves) {
        const int src = in_idx[e];
        const int dst = out_idx[e];
        const float m = tanhf(g1[src] + g2[dst]) * adj[e];

        const float2 v = *reinterpret_cast<const float2*>(x + (size_t)dst * HIDDEN + lane * 2);
        float* o = out + (size_t)src * HIDDEN + lane * 2;
        atomicAdd(o,     m * v.x);
        atomicAdd(o + 1, m * v.y);
    }
}

extern "C" void kernel_launch(void* const* d_in, const int* in_sizes, int n_in,
                              void* d_out, int out_size, void* d_ws, size_t ws_size,
                              hipStream_t stream) {
    const float* x        = (const float*)d_in[0];
    const float* w1       = (const float*)d_in[1];
    const float* w2       = (const float*)d_in[2];
    const float* adj_vals = (const float*)d_in[3];
    const int*   in_idx   = (const int*)d_in[4];
    const int*   out_idx  = (const int*)d_in[5];
    float* out = (float*)d_out;

    // gate scratch in workspace: 2 * N_NODES floats (800 KB)
    float* g1 = (float*)d_ws;
    float* g2 = g1 + N_NODES;

    // zero the output accumulator (poisoned by harness)
    hipMemsetAsync(d_out, 0, (size_t)N_NODES * HIDDEN * sizeof(float), stream);

    // gates: one wave per node, 4 nodes per 256-thread block
    {
        const int blocks = (N_NODES + 3) / 4;
        fagcn_gates<<<blocks, 256, 0, stream>>>(x, w1, w2, g1, g2);
    }

    // edge scatter: grid-stride, 16384 waves
    {
        const int blocks = 4096;
        fagcn_edges<<<blocks, 256, 0, stream>>>(x, adj_vals, in_idx, out_idx, g1, g2, out);
    }
}

// Round 2
// 475.430 us; speedup vs baseline: 2.8014x; 2.8014x over previous
//
#include <hip/hip_runtime.h>

#define N_NODES 100000
#define N_EDGES 1600000
#define HIDDEN  128

// ---------------------------------------------------------------------------
// Kernel 1: per-node gate scalars. One 64-lane wave per node.
// ---------------------------------------------------------------------------
__global__ void fagcn_gates(const float* __restrict__ x,
                            const float* __restrict__ w1,
                            const float* __restrict__ w2,
                            float* __restrict__ g1,
                            float* __restrict__ g2) {
    const int wave = (int)((blockIdx.x * blockDim.x + threadIdx.x) >> 6);
    const int lane = (int)(threadIdx.x & 63);
    if (wave >= N_NODES) return;

    const float2 xv  = *reinterpret_cast<const float2*>(x  + (size_t)wave * HIDDEN + lane * 2);
    const float2 w1v = *reinterpret_cast<const float2*>(w1 + lane * 2);
    const float2 w2v = *reinterpret_cast<const float2*>(w2 + lane * 2);

    float s1 = xv.x * w1v.x + xv.y * w1v.y;
    float s2 = xv.x * w2v.x + xv.y * w2v.y;

    #pragma unroll
    for (int off = 32; off > 0; off >>= 1) {
        s1 += __shfl_down(s1, off, 64);
        s2 += __shfl_down(s2, off, 64);
    }
    if (lane == 0) {
        g1[wave] = s1;
        g2[wave] = s2;
    }
}

// ---------------------------------------------------------------------------
// Kernel 2: histogram of in_idx into cursor[] (used as counts)
// ---------------------------------------------------------------------------
__global__ void fagcn_hist(const int* __restrict__ in_idx,
                           int* __restrict__ counts) {
    const int e = blockIdx.x * blockDim.x + threadIdx.x;
    if (e < N_EDGES) atomicAdd(&counts[in_idx[e]], 1);
}

// ---------------------------------------------------------------------------
// Kernel 3: exclusive scan of counts -> offsets. One block, 1024 threads.
// ---------------------------------------------------------------------------
__global__ void fagcn_scan(const int* __restrict__ counts,
                           int* __restrict__ offsets) {
    __shared__ int lsum[1024];
    const int t = (int)threadIdx.x;
    const int C = (N_NODES + 1023) / 1024;       // 98 per thread
    const int beg = t * C;
    const int end = (beg + C < N_NODES) ? beg + C : N_NODES;

    int s = 0;
    for (int i = beg; i < end; ++i) s += counts[i];
    lsum[t] = s;
    __syncthreads();

    // Hillis-Steele inclusive scan over 1024 thread sums
    for (int off = 1; off < 1024; off <<= 1) {
        int v = (t >= off) ? lsum[t - off] : 0;
        __syncthreads();
        lsum[t] += v;
        __syncthreads();
    }

    int prefix = (t == 0) ? 0 : lsum[t - 1];
    for (int i = beg; i < end; ++i) {
        offsets[i] = prefix;
        prefix += counts[i];
    }
    if (t == 1023) offsets[N_NODES] = N_EDGES;
}

// ---------------------------------------------------------------------------
// Kernel 4: bin edges into CSR order; compute the edge gate once here.
// ---------------------------------------------------------------------------
__global__ void fagcn_bin(const float* __restrict__ adj,
                          const int*   __restrict__ in_idx,
                          const int*   __restrict__ out_idx,
                          const float* __restrict__ g1,
                          const float* __restrict__ g2,
                          const int*   __restrict__ offsets,
                          int*         __restrict__ cursor,
                          int*         __restrict__ sdst,
                          float*       __restrict__ sm) {
    const int e = blockIdx.x * blockDim.x + threadIdx.x;
    if (e >= N_EDGES) return;
    const int src = in_idx[e];
    const int dst = out_idx[e];
    const float m = tanhf(g1[src] + g2[dst]) * adj[e];
    const int pos = offsets[src] + atomicAdd(&cursor[src], 1);
    sdst[pos] = dst;
    sm[pos]   = m;
}

// ---------------------------------------------------------------------------
// Kernel 5: gather-accumulate. One wave per node; lane owns dims [2l,2l+1].
// Register accumulation, single float2 store per lane. No output atomics.
// ---------------------------------------------------------------------------
__global__ void fagcn_gather(const float* __restrict__ x,
                             const int*   __restrict__ offsets,
                             const int*   __restrict__ sdst,
                             const float* __restrict__ sm,
                             float*       __restrict__ out) {
    const int wave = (int)((blockIdx.x * blockDim.x + threadIdx.x) >> 6);
    const int lane = (int)(threadIdx.x & 63);
    if (wave >= N_NODES) return;

    const int beg = offsets[wave];
    const int end = offsets[wave + 1];

    float2 acc0 = {0.f, 0.f}, acc1 = {0.f, 0.f};
    int e = beg;
    for (; e + 1 < end; e += 2) {
        const int   d0 = sdst[e];
        const int   d1 = sdst[e + 1];
        const float m0 = sm[e];
        const float m1 = sm[e + 1];
        const float2 v0 = *reinterpret_cast<const float2*>(x + (size_t)d0 * HIDDEN + lane * 2);
        const float2 v1 = *reinterpret_cast<const float2*>(x + (size_t)d1 * HIDDEN + lane * 2);
        acc0.x += m0 * v0.x; acc0.y += m0 * v0.y;
        acc1.x += m1 * v1.x; acc1.y += m1 * v1.y;
    }
    if (e < end) {
        const int   d = sdst[e];
        const float m = sm[e];
        const float2 v = *reinterpret_cast<const float2*>(x + (size_t)d * HIDDEN + lane * 2);
        acc0.x += m * v.x; acc0.y += m * v.y;
    }

    float2 r = {acc0.x + acc1.x, acc0.y + acc1.y};
    *reinterpret_cast<float2*>(out + (size_t)wave * HIDDEN + lane * 2) = r;
}

// ---------------------------------------------------------------------------
// Fallback (round-1 path) if workspace is too small for CSR build.
// ---------------------------------------------------------------------------
__global__ void fagcn_edges_atomic(const float* __restrict__ x,
                                   const float* __restrict__ adj,
                                   const int*   __restrict__ in_idx,
                                   const int*   __restrict__ out_idx,
                                   const float* __restrict__ g1,
                                   const float* __restrict__ g2,
                                   float* __restrict__ out) {
    const int lane   = (int)(threadIdx.x & 63);
    const int gwave  = (int)((blockIdx.x * blockDim.x + threadIdx.x) >> 6);
    const int nwaves = (int)((gridDim.x * blockDim.x) >> 6);
    for (int e = gwave; e < N_EDGES; e += nwaves) {
        const int src = in_idx[e];
        const int dst = out_idx[e];
        const float m = tanhf(g1[src] + g2[dst]) * adj[e];
        const float2 v = *reinterpret_cast<const float2*>(x + (size_t)dst * HIDDEN + lane * 2);
        float* o = out + (size_t)src * HIDDEN + lane * 2;
        atomicAdd(o,     m * v.x);
        atomicAdd(o + 1, m * v.y);
    }
}

extern "C" void kernel_launch(void* const* d_in, const int* in_sizes, int n_in,
                              void* d_out, int out_size, void* d_ws, size_t ws_size,
                              hipStream_t stream) {
    const float* x        = (const float*)d_in[0];
    const float* w1       = (const float*)d_in[1];
    const float* w2       = (const float*)d_in[2];
    const float* adj_vals = (const float*)d_in[3];
    const int*   in_idx   = (const int*)d_in[4];
    const int*   out_idx  = (const int*)d_in[5];
    float* out = (float*)d_out;

    // workspace layout (all 4-byte elements)
    float* g1      = (float*)d_ws;                 // N_NODES
    float* g2      = g1 + N_NODES;                 // N_NODES
    int*   offsets = (int*)(g2 + N_NODES);         // N_NODES + 1
    int*   cursor  = offsets + N_NODES + 1;        // N_NODES
    int*   sdst    = cursor + N_NODES;             // N_EDGES
    float* sm      = (float*)(sdst + N_EDGES);     // N_EDGES
    const size_t need = ((size_t)2 * N_NODES + (N_NODES + 1) + N_NODES
                         + (size_t)2 * N_EDGES) * sizeof(float);

    // gates: one wave per node
    fagcn_gates<<<(N_NODES + 3) / 4, 256, 0, stream>>>(x, w1, w2, g1, g2);

    if (ws_size >= need) {
        // zero counts (cursor doubles as counts for the histogram)
        hipMemsetAsync(cursor, 0, (size_t)N_NODES * sizeof(int), stream);
        fagcn_hist<<<(N_EDGES + 255) / 256, 256, 0, stream>>>(in_idx, cursor);
        fagcn_scan<<<1, 1024, 0, stream>>>(cursor, offsets);
        hipMemsetAsync(cursor, 0, (size_t)N_NODES * sizeof(int), stream);
        fagcn_bin<<<(N_EDGES + 255) / 256, 256, 0, stream>>>(
            adj_vals, in_idx, out_idx, g1, g2, offsets, cursor, sdst, sm);
        // every output row is written exactly once -> no d_out memset needed
        fagcn_gather<<<(N_NODES + 3) / 4, 256, 0, stream>>>(x, offsets, sdst, sm, out);
    } else {
        hipMemsetAsync(d_out, 0, (size_t)N_NODES * HIDDEN * sizeof(float), stream);
        fagcn_edges_atomic<<<4096, 256, 0, stream>>>(
            x, adj_vals, in_idx, out_idx, g1, g2, out);
    }
}

// Round 3
// 327.487 us; speedup vs baseline: 4.0670x; 1.4518x over previous
//
#include <hip/hip_runtime.h>

#define N_NODES 100000
#define N_EDGES 1600000
#define HIDDEN  128

// parallel-scan geometry
#define SCAN_C 16
#define SCAN_T ((N_NODES + SCAN_C - 1) / SCAN_C)      // 6250 chunk threads
#define SCAN_THREADS 6400                              // 25 blocks * 256 (padded)
#define SCAN_B (SCAN_THREADS / 256)                    // 25

// ---------------------------------------------------------------------------
// Kernel 1: per-node gate scalars. One 64-lane wave per node.
// ---------------------------------------------------------------------------
__global__ void fagcn_gates(const float* __restrict__ x,
                            const float* __restrict__ w1,
                            const float* __restrict__ w2,
                            float* __restrict__ g1,
                            float* __restrict__ g2) {
    const int wave = (int)((blockIdx.x * blockDim.x + threadIdx.x) >> 6);
    const int lane = (int)(threadIdx.x & 63);
    if (wave >= N_NODES) return;

    const float2 xv  = *reinterpret_cast<const float2*>(x  + (size_t)wave * HIDDEN + lane * 2);
    const float2 w1v = *reinterpret_cast<const float2*>(w1 + lane * 2);
    const float2 w2v = *reinterpret_cast<const float2*>(w2 + lane * 2);

    float s1 = xv.x * w1v.x + xv.y * w1v.y;
    float s2 = xv.x * w2v.x + xv.y * w2v.y;

    #pragma unroll
    for (int off = 32; off > 0; off >>= 1) {
        s1 += __shfl_down(s1, off, 64);
        s2 += __shfl_down(s2, off, 64);
    }
    if (lane == 0) {
        g1[wave] = s1;
        g2[wave] = s2;
    }
}

// ---------------------------------------------------------------------------
// Kernel 2: histogram of in_idx into counts[]
// ---------------------------------------------------------------------------
__global__ void fagcn_hist(const int* __restrict__ in_idx,
                           int* __restrict__ counts) {
    const int e = blockIdx.x * blockDim.x + threadIdx.x;
    if (e < N_EDGES) atomicAdd(&counts[in_idx[e]], 1);
}

// ---------------------------------------------------------------------------
// Scan phase 1: per-thread chunk sums. tid in [0, SCAN_THREADS).
// ---------------------------------------------------------------------------
__global__ void fagcn_scan1(const int* __restrict__ counts,
                            int* __restrict__ tsum) {
    const int t = blockIdx.x * blockDim.x + threadIdx.x;
    if (t >= SCAN_THREADS) return;
    int s = 0;
    if (t < SCAN_T) {
        const int beg = t * SCAN_C;
        const int end = (beg + SCAN_C < N_NODES) ? beg + SCAN_C : N_NODES;
        for (int i = beg; i < end; ++i) s += counts[i];
    }
    tsum[t] = s;
}

// ---------------------------------------------------------------------------
// Scan phase 2: exclusive scan of the SCAN_THREADS thread-sums (1 block).
// ---------------------------------------------------------------------------
__global__ void fagcn_scan2(int* __restrict__ tsum) {
    __shared__ int lsum[1024];
    const int t = (int)threadIdx.x;
    const int C = (SCAN_THREADS + 1023) / 1024;   // 7
    const int beg = t * C;
    const int end = (beg + C < SCAN_THREADS) ? beg + C : SCAN_THREADS;

    int s = 0;
    for (int i = beg; i < end; ++i) s += tsum[i];
    lsum[t] = s;
    __syncthreads();

    for (int off = 1; off < 1024; off <<= 1) {
        int v = (t >= off) ? lsum[t - off] : 0;
        __syncthreads();
        lsum[t] += v;
        __syncthreads();
    }

    int prefix = (t == 0) ? 0 : lsum[t - 1];
    for (int i = beg; i < end; ++i) {
        const int v = tsum[i];
        tsum[i] = prefix;
        prefix += v;
    }
}

// ---------------------------------------------------------------------------
// Scan phase 3: write exclusive offsets from chunk prefix + counts.
// ---------------------------------------------------------------------------
__global__ void fagcn_scan3(const int* __restrict__ counts,
                            const int* __restrict__ tsum,
                            int* __restrict__ offsets) {
    const int t = blockIdx.x * blockDim.x + threadIdx.x;
    if (t >= SCAN_T) return;
    const int beg = t * SCAN_C;
    const int end = (beg + SCAN_C < N_NODES) ? beg + SCAN_C : N_NODES;
    int prefix = tsum[t];
    for (int i = beg; i < end; ++i) {
        offsets[i] = prefix;
        prefix += counts[i];
    }
    if (t == 0) offsets[N_NODES] = N_EDGES;
}

// ---------------------------------------------------------------------------
// Kernel 4: bin edges into CSR order; compute the edge gate once here.
// ---------------------------------------------------------------------------
__global__ void fagcn_bin(const float* __restrict__ adj,
                          const int*   __restrict__ in_idx,
                          const int*   __restrict__ out_idx,
                          const float* __restrict__ g1,
                          const float* __restrict__ g2,
                          const int*   __restrict__ offsets,
                          int*         __restrict__ cursor,
                          int*         __restrict__ sdst,
                          float*       __restrict__ sm) {
    const int e = blockIdx.x * blockDim.x + threadIdx.x;
    if (e >= N_EDGES) return;
    const int src = in_idx[e];
    const int dst = out_idx[e];
    const float m = tanhf(g1[src] + g2[dst]) * adj[e];
    const int pos = offsets[src] + atomicAdd(&cursor[src], 1);
    sdst[pos] = dst;
    sm[pos]   = m;
}

// ---------------------------------------------------------------------------
// Kernel 5: gather-accumulate. One wave per node; lane owns dims [2l,2l+1].
// Register accumulation, single float2 store per lane. No output atomics.
// ---------------------------------------------------------------------------
__global__ void fagcn_gather(const float* __restrict__ x,
                             const int*   __restrict__ offsets,
                             const int*   __restrict__ sdst,
                             const float* __restrict__ sm,
                             float*       __restrict__ out) {
    const int wave = (int)((blockIdx.x * blockDim.x + threadIdx.x) >> 6);
    const int lane = (int)(threadIdx.x & 63);
    if (wave >= N_NODES) return;

    const int beg = offsets[wave];
    const int end = offsets[wave + 1];

    float2 acc0 = {0.f, 0.f}, acc1 = {0.f, 0.f};
    int e = beg;
    for (; e + 1 < end; e += 2) {
        const int   d0 = sdst[e];
        const int   d1 = sdst[e + 1];
        const float m0 = sm[e];
        const float m1 = sm[e + 1];
        const float2 v0 = *reinterpret_cast<const float2*>(x + (size_t)d0 * HIDDEN + lane * 2);
        const float2 v1 = *reinterpret_cast<const float2*>(x + (size_t)d1 * HIDDEN + lane * 2);
        acc0.x += m0 * v0.x; acc0.y += m0 * v0.y;
        acc1.x += m1 * v1.x; acc1.y += m1 * v1.y;
    }
    if (e < end) {
        const int   d = sdst[e];
        const float m = sm[e];
        const float2 v = *reinterpret_cast<const float2*>(x + (size_t)d * HIDDEN + lane * 2);
        acc0.x += m * v.x; acc0.y += m * v.y;
    }

    float2 r = {acc0.x + acc1.x, acc0.y + acc1.y};
    *reinterpret_cast<float2*>(out + (size_t)wave * HIDDEN + lane * 2) = r;
}

extern "C" void kernel_launch(void* const* d_in, const int* in_sizes, int n_in,
                              void* d_out, int out_size, void* d_ws, size_t ws_size,
                              hipStream_t stream) {
    const float* x        = (const float*)d_in[0];
    const float* w1       = (const float*)d_in[1];
    const float* w2       = (const float*)d_in[2];
    const float* adj_vals = (const float*)d_in[3];
    const int*   in_idx   = (const int*)d_in[4];
    const int*   out_idx  = (const int*)d_in[5];
    float* out = (float*)d_out;

    // workspace layout (all 4-byte elements)
    float* g1      = (float*)d_ws;                 // N_NODES
    float* g2      = g1 + N_NODES;                 // N_NODES
    int*   offsets = (int*)(g2 + N_NODES);         // N_NODES + 1
    int*   cursor  = offsets + N_NODES + 1;        // N_NODES
    int*   sdst    = cursor + N_NODES;             // N_EDGES
    float* sm      = (float*)(sdst + N_EDGES);     // N_EDGES
    int*   tsum    = (int*)(sm + N_EDGES);         // SCAN_THREADS

    // gates: one wave per node
    fagcn_gates<<<(N_NODES + 3) / 4, 256, 0, stream>>>(x, w1, w2, g1, g2);

    // histogram (cursor doubles as counts)
    hipMemsetAsync(cursor, 0, (size_t)N_NODES * sizeof(int), stream);
    fagcn_hist<<<(N_EDGES + 255) / 256, 256, 0, stream>>>(in_idx, cursor);

    // parallel exclusive scan: counts(cursor) -> offsets
    fagcn_scan1<<<SCAN_B, 256, 0, stream>>>(cursor, tsum);
    fagcn_scan2<<<1, 1024, 0, stream>>>(tsum);
    fagcn_scan3<<<SCAN_B, 256, 0, stream>>>(cursor, tsum, offsets);

    // bin edges into CSR order
    hipMemsetAsync(cursor, 0, (size_t)N_NODES * sizeof(int), stream);
    fagcn_bin<<<(N_EDGES + 255) / 256, 256, 0, stream>>>(
        adj_vals, in_idx, out_idx, g1, g2, offsets, cursor, sdst, sm);

    // gather: every output row written exactly once -> no d_out memset needed
    fagcn_gather<<<(N_NODES + 3) / 4, 256, 0, stream>>>(x, offsets, sdst, sm, out);
}

// Round 4
// 289.964 us; speedup vs baseline: 4.5933x; 1.1294x over previous
//
#include <hip/hip_runtime.h>

#define N_NODES 100000
#define N_EDGES 1600000
#define HIDDEN  128

// parallel-scan geometry
#define SCAN_C 16
#define SCAN_T ((N_NODES + SCAN_C - 1) / SCAN_C)      // 6250 chunk threads
#define SCAN_THREADS 6400                              // 25 blocks * 256 (padded)
#define SCAN_B (SCAN_THREADS / 256)                    // 25

// ---------------------------------------------------------------------------
// Kernel 1: per-node gate scalars. One 64-lane wave per node.
// ---------------------------------------------------------------------------
__global__ void fagcn_gates(const float* __restrict__ x,
                            const float* __restrict__ w1,
                            const float* __restrict__ w2,
                            float* __restrict__ g1,
                            float* __restrict__ g2) {
    const int wave = (int)((blockIdx.x * blockDim.x + threadIdx.x) >> 6);
    const int lane = (int)(threadIdx.x & 63);
    if (wave >= N_NODES) return;

    const float2 xv  = *reinterpret_cast<const float2*>(x  + (size_t)wave * HIDDEN + lane * 2);
    const float2 w1v = *reinterpret_cast<const float2*>(w1 + lane * 2);
    const float2 w2v = *reinterpret_cast<const float2*>(w2 + lane * 2);

    float s1 = xv.x * w1v.x + xv.y * w1v.y;
    float s2 = xv.x * w2v.x + xv.y * w2v.y;

    #pragma unroll
    for (int off = 32; off > 0; off >>= 1) {
        s1 += __shfl_down(s1, off, 64);
        s2 += __shfl_down(s2, off, 64);
    }
    if (lane == 0) {
        g1[wave] = s1;
        g2[wave] = s2;
    }
}

// ---------------------------------------------------------------------------
// Kernel 2: histogram of in_idx into counts[]
// ---------------------------------------------------------------------------
__global__ void fagcn_hist(const int* __restrict__ in_idx,
                           int* __restrict__ counts) {
    const int e = blockIdx.x * blockDim.x + threadIdx.x;
    if (e < N_EDGES) atomicAdd(&counts[in_idx[e]], 1);
}

// ---------------------------------------------------------------------------
// Scan phase 1: per-thread chunk sums.
// ---------------------------------------------------------------------------
__global__ void fagcn_scan1(const int* __restrict__ counts,
                            int* __restrict__ tsum) {
    const int t = blockIdx.x * blockDim.x + threadIdx.x;
    if (t >= SCAN_THREADS) return;
    int s = 0;
    if (t < SCAN_T) {
        const int beg = t * SCAN_C;
        const int end = (beg + SCAN_C < N_NODES) ? beg + SCAN_C : N_NODES;
        for (int i = beg; i < end; ++i) s += counts[i];
    }
    tsum[t] = s;
}

// ---------------------------------------------------------------------------
// Scan phase 2: exclusive scan of the thread-sums (1 block).
// ---------------------------------------------------------------------------
__global__ void fagcn_scan2(int* __restrict__ tsum) {
    __shared__ int lsum[1024];
    const int t = (int)threadIdx.x;
    const int C = (SCAN_THREADS + 1023) / 1024;   // 7
    const int beg = t * C;
    const int end = (beg + C < SCAN_THREADS) ? beg + C : SCAN_THREADS;

    int s = 0;
    for (int i = beg; i < end; ++i) s += tsum[i];
    lsum[t] = s;
    __syncthreads();

    for (int off = 1; off < 1024; off <<= 1) {
        int v = (t >= off) ? lsum[t - off] : 0;
        __syncthreads();
        lsum[t] += v;
        __syncthreads();
    }

    int prefix = (t == 0) ? 0 : lsum[t - 1];
    for (int i = beg; i < end; ++i) {
        const int v = tsum[i];
        tsum[i] = prefix;
        prefix += v;
    }
}

// ---------------------------------------------------------------------------
// Scan phase 3: write exclusive offsets from chunk prefix + counts.
// ---------------------------------------------------------------------------
__global__ void fagcn_scan3(const int* __restrict__ counts,
                            const int* __restrict__ tsum,
                            int* __restrict__ offsets) {
    const int t = blockIdx.x * blockDim.x + threadIdx.x;
    if (t >= SCAN_T) return;
    const int beg = t * SCAN_C;
    const int end = (beg + SCAN_C < N_NODES) ? beg + SCAN_C : N_NODES;
    int prefix = tsum[t];
    for (int i = beg; i < end; ++i) {
        offsets[i] = prefix;
        prefix += counts[i];
    }
    if (t == 0) offsets[N_NODES] = N_EDGES;
}

// ---------------------------------------------------------------------------
// Kernel 4: bin edges into CSR order. Packed (dst, m) -> one 8B scatter/edge.
// ---------------------------------------------------------------------------
__global__ void fagcn_bin(const float* __restrict__ adj,
                          const int*   __restrict__ in_idx,
                          const int*   __restrict__ out_idx,
                          const float* __restrict__ g1,
                          const float* __restrict__ g2,
                          const int*   __restrict__ offsets,
                          int*         __restrict__ cursor,
                          int2*        __restrict__ sedge) {
    const int e = blockIdx.x * blockDim.x + threadIdx.x;
    if (e >= N_EDGES) return;
    const int src = in_idx[e];
    const int dst = out_idx[e];
    const float m = tanhf(g1[src] + g2[dst]) * adj[e];
    const int pos = offsets[src] + atomicAdd(&cursor[src], 1);
    sedge[pos] = make_int2(dst, __float_as_int(m));
}

// ---------------------------------------------------------------------------
// Kernel 5: gather-accumulate. One wave per node.
// Half-wave per edge: lanes 0-31 take even CSR slots, 32-63 odd slots.
// Lane owns dims [4*(lane&31) .. +3] as float4. 2-deep unroll -> 4 rows
// in flight per wave. Halves combined with one xor-32 shuffle.
// ---------------------------------------------------------------------------
__global__ void fagcn_gather(const float* __restrict__ x,
                             const int*   __restrict__ offsets,
                             const int2*  __restrict__ sedge,
                             float*       __restrict__ out) {
    const int wave = (int)((blockIdx.x * blockDim.x + threadIdx.x) >> 6);
    const int lane = (int)(threadIdx.x & 63);
    if (wave >= N_NODES) return;

    const int beg  = offsets[wave];
    const int end  = offsets[wave + 1];
    const int half = lane >> 5;            // 0: even slots, 1: odd slots
    const int hl   = lane & 31;            // dim block [4hl, 4hl+3]

    float4 acc0 = {0.f, 0.f, 0.f, 0.f};
    float4 acc1 = {0.f, 0.f, 0.f, 0.f};

    int e = beg + half;
    for (; e + 2 < end; e += 4) {
        const int2 ed0 = sedge[e];
        const int2 ed1 = sedge[e + 2];
        const float m0 = __int_as_float(ed0.y);
        const float m1 = __int_as_float(ed1.y);
        const float4 v0 = *reinterpret_cast<const float4*>(x + (size_t)ed0.x * HIDDEN + hl * 4);
        const float4 v1 = *reinterpret_cast<const float4*>(x + (size_t)ed1.x * HIDDEN + hl * 4);
        acc0.x += m0 * v0.x; acc0.y += m0 * v0.y;
        acc0.z += m0 * v0.z; acc0.w += m0 * v0.w;
        acc1.x += m1 * v1.x; acc1.y += m1 * v1.y;
        acc1.z += m1 * v1.z; acc1.w += m1 * v1.w;
    }
    for (; e < end; e += 2) {
        const int2 ed = sedge[e];
        const float m = __int_as_float(ed.y);
        const float4 v = *reinterpret_cast<const float4*>(x + (size_t)ed.x * HIDDEN + hl * 4);
        acc0.x += m * v.x; acc0.y += m * v.y;
        acc0.z += m * v.z; acc0.w += m * v.w;
    }

    float4 a;
    a.x = acc0.x + acc1.x;
    a.y = acc0.y + acc1.y;
    a.z = acc0.z + acc1.z;
    a.w = acc0.w + acc1.w;

    // combine the two half-wave partials (xor-32 butterfly; both halves get sum)
    a.x += __shfl(a.x, lane ^ 32, 64);
    a.y += __shfl(a.y, lane ^ 32, 64);
    a.z += __shfl(a.z, lane ^ 32, 64);
    a.w += __shfl(a.w, lane ^ 32, 64);

    if (half == 0) {
        *reinterpret_cast<float4*>(out + (size_t)wave * HIDDEN + hl * 4) = a;
    }
}

extern "C" void kernel_launch(void* const* d_in, const int* in_sizes, int n_in,
                              void* d_out, int out_size, void* d_ws, size_t ws_size,
                              hipStream_t stream) {
    const float* x        = (const float*)d_in[0];
    const float* w1       = (const float*)d_in[1];
    const float* w2       = (const float*)d_in[2];
    const float* adj_vals = (const float*)d_in[3];
    const int*   in_idx   = (const int*)d_in[4];
    const int*   out_idx  = (const int*)d_in[5];
    float* out = (float*)d_out;

    // workspace layout: sedge first (8B aligned), then the small arrays
    int2*  sedge   = (int2*)d_ws;                  // N_EDGES int2 (12.8 MB)
    float* g1      = (float*)(sedge + N_EDGES);    // N_NODES
    float* g2      = g1 + N_NODES;                 // N_NODES
    int*   offsets = (int*)(g2 + N_NODES);         // N_NODES + 1
    int*   cursor  = offsets + N_NODES + 1;        // N_NODES
    int*   tsum    = cursor + N_NODES;             // SCAN_THREADS

    // gates: one wave per node
    fagcn_gates<<<(N_NODES + 3) / 4, 256, 0, stream>>>(x, w1, w2, g1, g2);

    // histogram (cursor doubles as counts)
    hipMemsetAsync(cursor, 0, (size_t)N_NODES * sizeof(int), stream);
    fagcn_hist<<<(N_EDGES + 255) / 256, 256, 0, stream>>>(in_idx, cursor);

    // parallel exclusive scan: counts(cursor) -> offsets
    fagcn_scan1<<<SCAN_B, 256, 0, stream>>>(cursor, tsum);
    fagcn_scan2<<<1, 1024, 0, stream>>>(tsum);
    fagcn_scan3<<<SCAN_B, 256, 0, stream>>>(cursor, tsum, offsets);

    // bin edges into CSR order (packed 8B scatter)
    hipMemsetAsync(cursor, 0, (size_t)N_NODES * sizeof(int), stream);
    fagcn_bin<<<(N_EDGES + 255) / 256, 256, 0, stream>>>(
        adj_vals, in_idx, out_idx, g1, g2, offsets, cursor, sedge);

    // gather: every output row written exactly once -> no d_out memset needed
    fagcn_gather<<<(N_NODES + 3) / 4, 256, 0, stream>>>(x, offsets, sedge, out);
}

// Round 5
// 272.987 us; speedup vs baseline: 4.8790x; 1.0622x over previous
//
#include <hip/hip_runtime.h>

#define N_NODES 100000
#define N_EDGES 1600000
#define HIDDEN  128

// parallel-scan geometry
#define SCAN_C 16
#define SCAN_T ((N_NODES + SCAN_C - 1) / SCAN_C)      // 6250 chunk threads
#define SCAN_THREADS 6400                              // 25 blocks * 256 (padded)
#define SCAN_B (SCAN_THREADS / 256)                    // 25

// ---------------------------------------------------------------------------
// Kernel 1: per-node gate scalars. Half-wave (32 lanes) per node, float4.
// Also zeroes cursor[node] so the histogram needs no separate memset.
// ---------------------------------------------------------------------------
__global__ void fagcn_gates(const float* __restrict__ x,
                            const float* __restrict__ w1,
                            const float* __restrict__ w2,
                            float* __restrict__ g1,
                            float* __restrict__ g2,
                            int*   __restrict__ cursor) {
    const int tid  = blockIdx.x * blockDim.x + threadIdx.x;
    const int node = tid >> 5;                 // 32 lanes per node
    const int hl   = (int)(threadIdx.x & 31);
    if (node >= N_NODES) return;

    const float4 xv  = *reinterpret_cast<const float4*>(x  + (size_t)node * HIDDEN + hl * 4);
    const float4 w1v = *reinterpret_cast<const float4*>(w1 + hl * 4);
    const float4 w2v = *reinterpret_cast<const float4*>(w2 + hl * 4);

    float s1 = xv.x * w1v.x + xv.y * w1v.y + xv.z * w1v.z + xv.w * w1v.w;
    float s2 = xv.x * w2v.x + xv.y * w2v.y + xv.z * w2v.z + xv.w * w2v.w;

    #pragma unroll
    for (int off = 16; off > 0; off >>= 1) {
        s1 += __shfl_down(s1, off, 32);
        s2 += __shfl_down(s2, off, 32);
    }
    if (hl == 0) {
        g1[node] = s1;
        g2[node] = s2;
        cursor[node] = 0;                      // pre-zero for the histogram
    }
}

// ---------------------------------------------------------------------------
// Kernel 2: histogram of in_idx into counts[] (cursor array, pre-zeroed)
// ---------------------------------------------------------------------------
__global__ void fagcn_hist(const int* __restrict__ in_idx,
                           int* __restrict__ counts) {
    const int e = blockIdx.x * blockDim.x + threadIdx.x;
    if (e < N_EDGES) atomicAdd(&counts[in_idx[e]], 1);
}

// ---------------------------------------------------------------------------
// Scan phase 1: per-thread chunk sums.
// ---------------------------------------------------------------------------
__global__ void fagcn_scan1(const int* __restrict__ counts,
                            int* __restrict__ tsum) {
    const int t = blockIdx.x * blockDim.x + threadIdx.x;
    if (t >= SCAN_THREADS) return;
    int s = 0;
    if (t < SCAN_T) {
        const int beg = t * SCAN_C;
        const int end = (beg + SCAN_C < N_NODES) ? beg + SCAN_C : N_NODES;
        for (int i = beg; i < end; ++i) s += counts[i];
    }
    tsum[t] = s;
}

// ---------------------------------------------------------------------------
// Scan phase 2: exclusive scan of the thread-sums (1 block).
// ---------------------------------------------------------------------------
__global__ void fagcn_scan2(int* __restrict__ tsum) {
    __shared__ int lsum[1024];
    const int t = (int)threadIdx.x;
    const int C = (SCAN_THREADS + 1023) / 1024;   // 7
    const int beg = t * C;
    const int end = (beg + C < SCAN_THREADS) ? beg + C : SCAN_THREADS;

    int s = 0;
    for (int i = beg; i < end; ++i) s += tsum[i];
    lsum[t] = s;
    __syncthreads();

    for (int off = 1; off < 1024; off <<= 1) {
        int v = (t >= off) ? lsum[t - off] : 0;
        __syncthreads();
        lsum[t] += v;
        __syncthreads();
    }

    int prefix = (t == 0) ? 0 : lsum[t - 1];
    for (int i = beg; i < end; ++i) {
        const int v = tsum[i];
        tsum[i] = prefix;
        prefix += v;
    }
}

// ---------------------------------------------------------------------------
// Scan phase 3: write exclusive offsets; re-zero counts (last reader) so the
// same array serves as the bin cursor with no memset dispatch.
// ---------------------------------------------------------------------------
__global__ void fagcn_scan3(int* counts,                 // aliases cursor!
                            const int* __restrict__ tsum,
                            int* __restrict__ offsets) {
    const int t = blockIdx.x * blockDim.x + threadIdx.x;
    if (t >= SCAN_T) return;
    const int beg = t * SCAN_C;
    const int end = (beg + SCAN_C < N_NODES) ? beg + SCAN_C : N_NODES;
    int prefix = tsum[t];
    for (int i = beg; i < end; ++i) {
        const int c = counts[i];
        offsets[i] = prefix;
        prefix += c;
        counts[i] = 0;                       // becomes bin's cursor
    }
    if (t == 0) offsets[N_NODES] = N_EDGES;
}

// ---------------------------------------------------------------------------
// Kernel 4: bin edges into CSR order. Packed (dst, m) -> one 8B scatter/edge.
// ---------------------------------------------------------------------------
__global__ void fagcn_bin(const float* __restrict__ adj,
                          const int*   __restrict__ in_idx,
                          const int*   __restrict__ out_idx,
                          const float* __restrict__ g1,
                          const float* __restrict__ g2,
                          const int*   __restrict__ offsets,
                          int*         __restrict__ cursor,
                          int2*        __restrict__ sedge) {
    const int e = blockIdx.x * blockDim.x + threadIdx.x;
    if (e >= N_EDGES) return;
    const int src = in_idx[e];
    const int dst = out_idx[e];
    const float m = tanhf(g1[src] + g2[dst]) * adj[e];
    const int pos = offsets[src] + atomicAdd(&cursor[src], 1);
    sedge[pos] = make_int2(dst, __float_as_int(m));
}

// ---------------------------------------------------------------------------
// Kernel 5: gather-accumulate. One wave per node.
// Half-wave per CSR-slot-parity; lane owns dims [4*(lane&31)..+3] as float4.
// 4-deep unroll per half -> 8 rows in flight per wave.
// ---------------------------------------------------------------------------
__global__ void fagcn_gather(const float* __restrict__ x,
                             const int*   __restrict__ offsets,
                             const int2*  __restrict__ sedge,
                             float*       __restrict__ out) {
    const int wave = (int)((blockIdx.x * blockDim.x + threadIdx.x) >> 6);
    const int lane = (int)(threadIdx.x & 63);
    if (wave >= N_NODES) return;

    const int beg  = offsets[wave];
    const int end  = offsets[wave + 1];
    const int half = lane >> 5;            // 0: even slots, 1: odd slots
    const int hl   = lane & 31;            // dim block [4hl, 4hl+3]

    float4 a0 = {0.f, 0.f, 0.f, 0.f};
    float4 a1 = {0.f, 0.f, 0.f, 0.f};
    float4 a2 = {0.f, 0.f, 0.f, 0.f};
    float4 a3 = {0.f, 0.f, 0.f, 0.f};

    int e = beg + half;
    for (; e + 6 < end; e += 8) {          // 4 slots per half per iteration
        const int2 ed0 = sedge[e];
        const int2 ed1 = sedge[e + 2];
        const int2 ed2 = sedge[e + 4];
        const int2 ed3 = sedge[e + 6];
        const float4 v0 = *reinterpret_cast<const float4*>(x + (size_t)ed0.x * HIDDEN + hl * 4);
        const float4 v1 = *reinterpret_cast<const float4*>(x + (size_t)ed1.x * HIDDEN + hl * 4);
        const float4 v2 = *reinterpret_cast<const float4*>(x + (size_t)ed2.x * HIDDEN + hl * 4);
        const float4 v3 = *reinterpret_cast<const float4*>(x + (size_t)ed3.x * HIDDEN + hl * 4);
        const float m0 = __int_as_float(ed0.y);
        const float m1 = __int_as_float(ed1.y);
        const float m2 = __int_as_float(ed2.y);
        const float m3 = __int_as_float(ed3.y);
        a0.x += m0 * v0.x; a0.y += m0 * v0.y; a0.z += m0 * v0.z; a0.w += m0 * v0.w;
        a1.x += m1 * v1.x; a1.y += m1 * v1.y; a1.z += m1 * v1.z; a1.w += m1 * v1.w;
        a2.x += m2 * v2.x; a2.y += m2 * v2.y; a2.z += m2 * v2.z; a2.w += m2 * v2.w;
        a3.x += m3 * v3.x; a3.y += m3 * v3.y; a3.z += m3 * v3.z; a3.w += m3 * v3.w;
    }
    for (; e < end; e += 2) {
        const int2 ed = sedge[e];
        const float m = __int_as_float(ed.y);
        const float4 v = *reinterpret_cast<const float4*>(x + (size_t)ed.x * HIDDEN + hl * 4);
        a0.x += m * v.x; a0.y += m * v.y; a0.z += m * v.z; a0.w += m * v.w;
    }

    float4 a;
    a.x = (a0.x + a1.x) + (a2.x + a3.x);
    a.y = (a0.y + a1.y) + (a2.y + a3.y);
    a.z = (a0.z + a1.z) + (a2.z + a3.z);
    a.w = (a0.w + a1.w) + (a2.w + a3.w);

    // combine the two half-wave partials (xor-32 butterfly)
    a.x += __shfl(a.x, lane ^ 32, 64);
    a.y += __shfl(a.y, lane ^ 32, 64);
    a.z += __shfl(a.z, lane ^ 32, 64);
    a.w += __shfl(a.w, lane ^ 32, 64);

    if (half == 0) {
        *reinterpret_cast<float4*>(out + (size_t)wave * HIDDEN + hl * 4) = a;
    }
}

extern "C" void kernel_launch(void* const* d_in, const int* in_sizes, int n_in,
                              void* d_out, int out_size, void* d_ws, size_t ws_size,
                              hipStream_t stream) {
    const float* x        = (const float*)d_in[0];
    const float* w1       = (const float*)d_in[1];
    const float* w2       = (const float*)d_in[2];
    const float* adj_vals = (const float*)d_in[3];
    const int*   in_idx   = (const int*)d_in[4];
    const int*   out_idx  = (const int*)d_in[5];
    float* out = (float*)d_out;

    // workspace layout: sedge first (8B aligned), then the small arrays
    int2*  sedge   = (int2*)d_ws;                  // N_EDGES int2 (12.8 MB)
    float* g1      = (float*)(sedge + N_EDGES);    // N_NODES
    float* g2      = g1 + N_NODES;                 // N_NODES
    int*   offsets = (int*)(g2 + N_NODES);         // N_NODES + 1
    int*   cursor  = offsets + N_NODES + 1;        // N_NODES (counts/cursor)
    int*   tsum    = cursor + N_NODES;             // SCAN_THREADS

    // gates (also zeroes cursor): half-wave per node
    fagcn_gates<<<(N_NODES * 32 + 255) / 256, 256, 0, stream>>>(
        x, w1, w2, g1, g2, cursor);

    // histogram into cursor
    fagcn_hist<<<(N_EDGES + 255) / 256, 256, 0, stream>>>(in_idx, cursor);

    // parallel exclusive scan: counts(cursor) -> offsets; scan3 re-zeroes cursor
    fagcn_scan1<<<SCAN_B, 256, 0, stream>>>(cursor, tsum);
    fagcn_scan2<<<1, 1024, 0, stream>>>(tsum);
    fagcn_scan3<<<SCAN_B, 256, 0, stream>>>(cursor, tsum, offsets);

    // bin edges into CSR order (packed 8B scatter)
    fagcn_bin<<<(N_EDGES + 255) / 256, 256, 0, stream>>>(
        adj_vals, in_idx, out_idx, g1, g2, offsets, cursor, sedge);

    // gather: every output row written exactly once -> no d_out memset needed
    fagcn_gather<<<(N_NODES + 3) / 4, 256, 0, stream>>>(x, offsets, sedge, out);
}

// Round 6
// 231.911 us; speedup vs baseline: 5.7431x; 1.1771x over previous
//
#include <hip/hip_runtime.h>

#define N_NODES 100000
#define N_EDGES 1600000
#define HIDDEN  128

// parallel-scan geometry
#define SCAN_C 16
#define SCAN_T ((N_NODES + SCAN_C - 1) / SCAN_C)      // 6250 chunk threads
#define SCAN_THREADS 6400                              // 25 blocks * 256 (padded)
#define SCAN_B (SCAN_THREADS / 256)                    // 25

// float -> bf16 round-to-nearest-even (bit arithmetic, no API dependence)
__device__ __forceinline__ ushort f2bf(float f) {
    unsigned int u = __float_as_uint(f);
    u = (u + 0x7FFFu + ((u >> 16) & 1u)) >> 16;
    return (ushort)u;
}

// ---------------------------------------------------------------------------
// Kernel 1: per-node gate scalars. Half-wave (32 lanes) per node, float4.
// Also zeroes cursor[node] and (optionally) writes the bf16 copy of x.
// ---------------------------------------------------------------------------
__global__ void fagcn_gates(const float* __restrict__ x,
                            const float* __restrict__ w1,
                            const float* __restrict__ w2,
                            float* __restrict__ g1,
                            float* __restrict__ g2,
                            int*   __restrict__ cursor,
                            ushort* __restrict__ xh,
                            int write_xh) {
    const int tid  = blockIdx.x * blockDim.x + threadIdx.x;
    const int node = tid >> 5;                 // 32 lanes per node
    const int hl   = (int)(threadIdx.x & 31);
    if (node >= N_NODES) return;

    const float4 xv  = *reinterpret_cast<const float4*>(x  + (size_t)node * HIDDEN + hl * 4);
    const float4 w1v = *reinterpret_cast<const float4*>(w1 + hl * 4);
    const float4 w2v = *reinterpret_cast<const float4*>(w2 + hl * 4);

    if (write_xh) {
        ushort4 h;
        h.x = f2bf(xv.x); h.y = f2bf(xv.y); h.z = f2bf(xv.z); h.w = f2bf(xv.w);
        *reinterpret_cast<ushort4*>(xh + (size_t)node * HIDDEN + hl * 4) = h;
    }

    float s1 = xv.x * w1v.x + xv.y * w1v.y + xv.z * w1v.z + xv.w * w1v.w;
    float s2 = xv.x * w2v.x + xv.y * w2v.y + xv.z * w2v.z + xv.w * w2v.w;

    #pragma unroll
    for (int off = 16; off > 0; off >>= 1) {
        s1 += __shfl_down(s1, off, 32);
        s2 += __shfl_down(s2, off, 32);
    }
    if (hl == 0) {
        g1[node] = s1;
        g2[node] = s2;
        cursor[node] = 0;                      // pre-zero for the histogram
    }
}

// ---------------------------------------------------------------------------
// Kernel 2: histogram of in_idx into counts[] (cursor array, pre-zeroed)
// ---------------------------------------------------------------------------
__global__ void fagcn_hist(const int* __restrict__ in_idx,
                           int* __restrict__ counts) {
    const int e = blockIdx.x * blockDim.x + threadIdx.x;
    if (e < N_EDGES) atomicAdd(&counts[in_idx[e]], 1);
}

// ---------------------------------------------------------------------------
// Scan phase 1: per-thread chunk sums.
// ---------------------------------------------------------------------------
__global__ void fagcn_scan1(const int* __restrict__ counts,
                            int* __restrict__ tsum) {
    const int t = blockIdx.x * blockDim.x + threadIdx.x;
    if (t >= SCAN_THREADS) return;
    int s = 0;
    if (t < SCAN_T) {
        const int beg = t * SCAN_C;
        const int end = (beg + SCAN_C < N_NODES) ? beg + SCAN_C : N_NODES;
        for (int i = beg; i < end; ++i) s += counts[i];
    }
    tsum[t] = s;
}

// ---------------------------------------------------------------------------
// Scan phase 2: exclusive scan of the thread-sums (1 block).
// ---------------------------------------------------------------------------
__global__ void fagcn_scan2(int* __restrict__ tsum) {
    __shared__ int lsum[1024];
    const int t = (int)threadIdx.x;
    const int C = (SCAN_THREADS + 1023) / 1024;   // 7
    const int beg = t * C;
    const int end = (beg + C < SCAN_THREADS) ? beg + C : SCAN_THREADS;

    int s = 0;
    for (int i = beg; i < end; ++i) s += tsum[i];
    lsum[t] = s;
    __syncthreads();

    for (int off = 1; off < 1024; off <<= 1) {
        int v = (t >= off) ? lsum[t - off] : 0;
        __syncthreads();
        lsum[t] += v;
        __syncthreads();
    }

    int prefix = (t == 0) ? 0 : lsum[t - 1];
    for (int i = beg; i < end; ++i) {
        const int v = tsum[i];
        tsum[i] = prefix;
        prefix += v;
    }
}

// ---------------------------------------------------------------------------
// Scan phase 3: write exclusive offsets; re-zero counts (last reader) so the
// same array serves as the bin cursor with no memset dispatch.
// ---------------------------------------------------------------------------
__global__ void fagcn_scan3(int* counts,                 // aliases cursor!
                            const int* __restrict__ tsum,
                            int* __restrict__ offsets) {
    const int t = blockIdx.x * blockDim.x + threadIdx.x;
    if (t >= SCAN_T) return;
    const int beg = t * SCAN_C;
    const int end = (beg + SCAN_C < N_NODES) ? beg + SCAN_C : N_NODES;
    int prefix = tsum[t];
    for (int i = beg; i < end; ++i) {
        const int c = counts[i];
        offsets[i] = prefix;
        prefix += c;
        counts[i] = 0;                       // becomes bin's cursor
    }
    if (t == 0) offsets[N_NODES] = N_EDGES;
}

// ---------------------------------------------------------------------------
// Kernel 4: bin edges into CSR order. Packed (dst, m) -> one 8B scatter/edge.
// ---------------------------------------------------------------------------
__global__ void fagcn_bin(const float* __restrict__ adj,
                          const int*   __restrict__ in_idx,
                          const int*   __restrict__ out_idx,
                          const float* __restrict__ g1,
                          const float* __restrict__ g2,
                          const int*   __restrict__ offsets,
                          int*         __restrict__ cursor,
                          int2*        __restrict__ sedge) {
    const int e = blockIdx.x * blockDim.x + threadIdx.x;
    if (e >= N_EDGES) return;
    const int src = in_idx[e];
    const int dst = out_idx[e];
    const float m = tanhf(g1[src] + g2[dst]) * adj[e];
    const int pos = offsets[src] + atomicAdd(&cursor[src], 1);
    sedge[pos] = make_int2(dst, __float_as_int(m));
}

// ---------------------------------------------------------------------------
// fma 8 bf16 elements (packed in a uint4) into a[0..7]
// ---------------------------------------------------------------------------
__device__ __forceinline__ void acc8(float* a, uint4 v, float m) {
    const unsigned int u[4] = {v.x, v.y, v.z, v.w};
    #pragma unroll
    for (int i = 0; i < 4; ++i) {
        const float lo = __uint_as_float(u[i] << 16);
        const float hi = __uint_as_float(u[i] & 0xFFFF0000u);
        a[2 * i]     += m * lo;
        a[2 * i + 1] += m * hi;
    }
}

// ---------------------------------------------------------------------------
// Kernel 5 (bf16): gather-accumulate. One wave per node.
// 16-lane group per CSR-slot-phase (4 phases); lane owns dims [8ql..8ql+7]
// as one 16B bf16x8 load. 4-deep unroll -> 16 rows (64 lines) in flight.
// ---------------------------------------------------------------------------
__global__ void fagcn_gather_bf16(const ushort* __restrict__ xh,
                                  const int*   __restrict__ offsets,
                                  const int2*  __restrict__ sedge,
                                  float*       __restrict__ out) {
    const int wave = (int)((blockIdx.x * blockDim.x + threadIdx.x) >> 6);
    const int lane = (int)(threadIdx.x & 63);
    if (wave >= N_NODES) return;

    const int beg = offsets[wave];
    const int end = offsets[wave + 1];
    const int q   = lane >> 4;             // slot phase 0..3
    const int ql  = lane & 15;             // dim block [8ql, 8ql+8)

    float a[8] = {0.f, 0.f, 0.f, 0.f, 0.f, 0.f, 0.f, 0.f};
    float b[8] = {0.f, 0.f, 0.f, 0.f, 0.f, 0.f, 0.f, 0.f};

    int e = beg + q;
    for (; e + 12 < end; e += 16) {        // phases interleave: stride 4
        const int2 ed0 = sedge[e];
        const int2 ed1 = sedge[e + 4];
        const int2 ed2 = sedge[e + 8];
        const int2 ed3 = sedge[e + 12];
        const uint4 v0 = *reinterpret_cast<const uint4*>(xh + (size_t)ed0.x * HIDDEN + ql * 8);
        const uint4 v1 = *reinterpret_cast<const uint4*>(xh + (size_t)ed1.x * HIDDEN + ql * 8);
        const uint4 v2 = *reinterpret_cast<const uint4*>(xh + (size_t)ed2.x * HIDDEN + ql * 8);
        const uint4 v3 = *reinterpret_cast<const uint4*>(xh + (size_t)ed3.x * HIDDEN + ql * 8);
        acc8(a, v0, __int_as_float(ed0.y));
        acc8(b, v1, __int_as_float(ed1.y));
        acc8(a, v2, __int_as_float(ed2.y));
        acc8(b, v3, __int_as_float(ed3.y));
    }
    for (; e < end; e += 4) {
        const int2 ed = sedge[e];
        const uint4 v = *reinterpret_cast<const uint4*>(xh + (size_t)ed.x * HIDDEN + ql * 8);
        acc8(a, v, __int_as_float(ed.y));
    }

    float r[8];
    #pragma unroll
    for (int i = 0; i < 8; ++i) r[i] = a[i] + b[i];
    // combine the 4 slot-phase groups: xor-16 then xor-32 butterflies
    #pragma unroll
    for (int i = 0; i < 8; ++i) r[i] += __shfl(r[i], lane ^ 16, 64);
    #pragma unroll
    for (int i = 0; i < 8; ++i) r[i] += __shfl(r[i], lane ^ 32, 64);

    if (lane < 16) {
        float* o = out + (size_t)wave * HIDDEN + ql * 8;
        float4 lo = {r[0], r[1], r[2], r[3]};
        float4 hi = {r[4], r[5], r[6], r[7]};
        *reinterpret_cast<float4*>(o)     = lo;
        *reinterpret_cast<float4*>(o + 4) = hi;
    }
}

// ---------------------------------------------------------------------------
// Kernel 5 (f32 fallback, round-5 version): used if ws can't hold xh.
// ---------------------------------------------------------------------------
__global__ void fagcn_gather_f32(const float* __restrict__ x,
                                 const int*   __restrict__ offsets,
                                 const int2*  __restrict__ sedge,
                                 float*       __restrict__ out) {
    const int wave = (int)((blockIdx.x * blockDim.x + threadIdx.x) >> 6);
    const int lane = (int)(threadIdx.x & 63);
    if (wave >= N_NODES) return;

    const int beg  = offsets[wave];
    const int end  = offsets[wave + 1];
    const int half = lane >> 5;
    const int hl   = lane & 31;

    float4 a0 = {0.f, 0.f, 0.f, 0.f};
    float4 a1 = {0.f, 0.f, 0.f, 0.f};

    int e = beg + half;
    for (; e + 2 < end; e += 4) {
        const int2 ed0 = sedge[e];
        const int2 ed1 = sedge[e + 2];
        const float m0 = __int_as_float(ed0.y);
        const float m1 = __int_as_float(ed1.y);
        const float4 v0 = *reinterpret_cast<const float4*>(x + (size_t)ed0.x * HIDDEN + hl * 4);
        const float4 v1 = *reinterpret_cast<const float4*>(x + (size_t)ed1.x * HIDDEN + hl * 4);
        a0.x += m0 * v0.x; a0.y += m0 * v0.y; a0.z += m0 * v0.z; a0.w += m0 * v0.w;
        a1.x += m1 * v1.x; a1.y += m1 * v1.y; a1.z += m1 * v1.z; a1.w += m1 * v1.w;
    }
    for (; e < end; e += 2) {
        const int2 ed = sedge[e];
        const float m = __int_as_float(ed.y);
        const float4 v = *reinterpret_cast<const float4*>(x + (size_t)ed.x * HIDDEN + hl * 4);
        a0.x += m * v.x; a0.y += m * v.y; a0.z += m * v.z; a0.w += m * v.w;
    }

    float4 a;
    a.x = a0.x + a1.x; a.y = a0.y + a1.y; a.z = a0.z + a1.z; a.w = a0.w + a1.w;
    a.x += __shfl(a.x, lane ^ 32, 64);
    a.y += __shfl(a.y, lane ^ 32, 64);
    a.z += __shfl(a.z, lane ^ 32, 64);
    a.w += __shfl(a.w, lane ^ 32, 64);
    if (half == 0) {
        *reinterpret_cast<float4*>(out + (size_t)wave * HIDDEN + hl * 4) = a;
    }
}

extern "C" void kernel_launch(void* const* d_in, const int* in_sizes, int n_in,
                              void* d_out, int out_size, void* d_ws, size_t ws_size,
                              hipStream_t stream) {
    const float* x        = (const float*)d_in[0];
    const float* w1       = (const float*)d_in[1];
    const float* w2       = (const float*)d_in[2];
    const float* adj_vals = (const float*)d_in[3];
    const int*   in_idx   = (const int*)d_in[4];
    const int*   out_idx  = (const int*)d_in[5];
    float* out = (float*)d_out;

    const size_t small_elems = (size_t)2 * N_NODES        // g1,g2
                             + (N_NODES + 1)              // offsets
                             + N_NODES                    // cursor
                             + SCAN_THREADS;              // tsum
    const size_t need_bf16 = (size_t)N_NODES * HIDDEN * 2     // xh
                           + (size_t)N_EDGES * 8               // sedge
                           + small_elems * 4;
    const int use_bf16 = (ws_size >= need_bf16);

    ushort* xh;
    int2*   sedge;
    if (use_bf16) {
        xh    = (ushort*)d_ws;                                 // 25.6 MB
        sedge = (int2*)(xh + (size_t)N_NODES * HIDDEN);        // 12.8 MB
    } else {
        xh    = (ushort*)d_ws;   // unused
        sedge = (int2*)d_ws;
    }
    float* g1      = (float*)(sedge + N_EDGES);
    float* g2      = g1 + N_NODES;
    int*   offsets = (int*)(g2 + N_NODES);
    int*   cursor  = offsets + N_NODES + 1;
    int*   tsum    = cursor + N_NODES;

    // gates (also zeroes cursor, writes bf16 x copy): half-wave per node
    fagcn_gates<<<(N_NODES * 32 + 255) / 256, 256, 0, stream>>>(
        x, w1, w2, g1, g2, cursor, xh, use_bf16);

    // histogram into cursor
    fagcn_hist<<<(N_EDGES + 255) / 256, 256, 0, stream>>>(in_idx, cursor);

    // parallel exclusive scan: counts(cursor) -> offsets; scan3 re-zeroes cursor
    fagcn_scan1<<<SCAN_B, 256, 0, stream>>>(cursor, tsum);
    fagcn_scan2<<<1, 1024, 0, stream>>>(tsum);
    fagcn_scan3<<<SCAN_B, 256, 0, stream>>>(cursor, tsum, offsets);

    // bin edges into CSR order (packed 8B scatter)
    fagcn_bin<<<(N_EDGES + 255) / 256, 256, 0, stream>>>(
        adj_vals, in_idx, out_idx, g1, g2, offsets, cursor, sedge);

    // gather: every output row written exactly once -> no d_out memset needed
    if (use_bf16) {
        fagcn_gather_bf16<<<(N_NODES + 3) / 4, 256, 0, stream>>>(
            xh, offsets, sedge, out);
    } else {
        fagcn_gather_f32<<<(N_NODES + 3) / 4, 256, 0, stream>>>(
            x, offsets, sedge, out);
    }
}